// Round 1
// baseline (398.667 us; speedup 1.0000x reference)
//
#include <hip/hip_runtime.h>
#include <math.h>

#define NB_ 512
#define B_ 32
#define H_ 16
#define D_ 576
#define KV_ 512
#define BS_ 128
#define SCALE_ 0.07216878364870323f  // 192^-0.5

// Workspace as device globals: k1 fully writes before k2 reads, every call.
__device__ float g_o[NB_ * H_ * KV_];   // unscaled per-block output, 16.8 MB
__device__ float g_bm[NB_ * H_];        // per-block max
__device__ float g_bs[NB_ * H_];        // per-block sum

// One workgroup per block n. 256 threads = 4 waves; wave w owns heads 4w..4w+3.
__global__ __launch_bounds__(256) void mla_block_kernel(
    const float* __restrict__ query,
    const float* __restrict__ key_cache,
    const float* __restrict__ block_bias,
    const int* __restrict__ block_list,
    const int* __restrict__ block_groups)
{
    // region1: phase1 q[16][576] (36864B); phase2 vt[16][512] (32768B) + p[16][128] (8192B)
    __shared__ float region1[10240];
    __shared__ float kt[128 * 36];      // K chunk [128 s][32 d + 4 pad], 18432B
    float* q_s = region1;
    float* vt  = region1;
    float* p_s = region1 + 8192;

    const int tid = threadIdx.x;
    const int n   = blockIdx.x;
    const int b   = block_groups[n];
    const float* K = key_cache + (long)block_list[n] * (BS_ * D_);
    const float* Q = query + (long)b * (H_ * D_);

    // ---- stage scaled q into LDS (16*576 = 2304 float4) ----
    {
        const float4* Q4 = (const float4*)Q;
        float4* S4 = (float4*)q_s;
#pragma unroll
        for (int i = 0; i < 9; ++i) {
            int idx = tid + 256 * i;
            float4 v = Q4[idx];
            v.x *= SCALE_; v.y *= SCALE_; v.z *= SCALE_; v.w *= SCALE_;
            S4[idx] = v;
        }
    }

    const int hg = tid >> 6;   // wave id -> heads 4hg..4hg+3
    const int sl = tid & 63;   // s lane: covers s = sl and s = sl+64

    float acc0[4] = {0.f, 0.f, 0.f, 0.f};
    float acc1[4] = {0.f, 0.f, 0.f, 0.f};

    // ---- phase 1: attn = q @ K^T, streamed in d-chunks of 32 ----
    for (int dc = 0; dc < D_; dc += 32) {
        __syncthreads();   // prev chunk reads done (also guards q staging before 1st compute)
#pragma unroll
        for (int i = 0; i < 4; ++i) {
            int flat = tid + 256 * i;            // 1024 float4 = 128 rows x 8
            int s = flat >> 3;
            int c = (flat & 7) << 2;
            *(float4*)(kt + s * 36 + c) = *(const float4*)(K + (long)s * D_ + dc + c);
        }
        __syncthreads();
#pragma unroll
        for (int d4 = 0; d4 < 32; d4 += 4) {
            float4 k0 = *(const float4*)(kt + sl * 36 + d4);
            float4 k1 = *(const float4*)(kt + (sl + 64) * 36 + d4);
#pragma unroll
            for (int i = 0; i < 4; ++i) {
                float4 qv = *(const float4*)(q_s + (4 * hg + i) * D_ + dc + d4);
                acc0[i] += qv.x * k0.x + qv.y * k0.y + qv.z * k0.z + qv.w * k0.w;
                acc1[i] += qv.x * k1.x + qv.y * k1.y + qv.z * k1.z + qv.w * k1.w;
            }
        }
    }

    // ---- softmax (per-wave: each wave owns its 4 heads entirely) ----
    float bias0 = block_bias[n * BS_ + sl];
    float bias1 = block_bias[n * BS_ + sl + 64];
    __syncthreads();   // all q/kt reads done before p overwrites region1 tail
#pragma unroll
    for (int i = 0; i < 4; ++i) {
        float a0 = acc0[i] + bias0;
        float a1 = acc1[i] + bias1;
        float m = fmaxf(a0, a1);
#pragma unroll
        for (int off = 32; off; off >>= 1) m = fmaxf(m, __shfl_xor(m, off));
        float p0 = __expf(a0 - m);
        float p1 = __expf(a1 - m);
        float s2 = p0 + p1;
#pragma unroll
        for (int off = 32; off; off >>= 1) s2 += __shfl_xor(s2, off);
        int h = 4 * hg + i;
        p_s[h * BS_ + sl] = p0;
        p_s[h * BS_ + sl + 64] = p1;
        if (sl == 0) {
            g_bm[n * H_ + h] = m;
            g_bs[n * H_ + h] = s2;
        }
    }

    // ---- phase 2: o = p @ V, V streamed in s-chunks of 16 ----
    float4 oa0[4], oa1[4];
#pragma unroll
    for (int i = 0; i < 4; ++i) {
        oa0[i] = make_float4(0.f, 0.f, 0.f, 0.f);
        oa1[i] = make_float4(0.f, 0.f, 0.f, 0.f);
    }

    for (int sc = 0; sc < BS_; sc += 16) {
        __syncthreads();   // p writes / prev tile reads complete
#pragma unroll
        for (int i = 0; i < 8; ++i) {
            int flat = tid + 256 * i;           // 2048 float4 = 16 rows x 128
            int s = flat >> 7;
            int c = (flat & 127) << 2;
            *(float4*)(vt + s * KV_ + c) = *(const float4*)(K + (long)(sc + s) * D_ + c);
        }
        __syncthreads();
#pragma unroll 4
        for (int s = 0; s < 16; ++s) {
            float4 v0 = *(const float4*)(vt + s * KV_ + 4 * sl);
            float4 v1 = *(const float4*)(vt + s * KV_ + 256 + 4 * sl);
#pragma unroll
            for (int i = 0; i < 4; ++i) {
                float pv = p_s[(4 * hg + i) * BS_ + sc + s];
                oa0[i].x += pv * v0.x; oa0[i].y += pv * v0.y;
                oa0[i].z += pv * v0.z; oa0[i].w += pv * v0.w;
                oa1[i].x += pv * v1.x; oa1[i].y += pv * v1.y;
                oa1[i].z += pv * v1.z; oa1[i].w += pv * v1.w;
            }
        }
    }

    // ---- write unscaled o ----
    float* op = g_o + (long)n * H_ * KV_;
#pragma unroll
    for (int i = 0; i < 4; ++i) {
        *(float4*)(op + (4 * hg + i) * KV_ + 4 * sl) = oa0[i];
        *(float4*)(op + (4 * hg + i) * KV_ + 256 + 4 * sl) = oa1[i];
    }
}

// One workgroup per (b,h). Group combine: rescale each block's o and sum.
__global__ __launch_bounds__(128) void mla_combine_kernel(float* __restrict__ out)
{
    const int bh = blockIdx.x;
    const int b = bh >> 4;
    const int h = bh & 15;
    const int tid = threadIdx.x;

    float bm[16];
    float m = -1e30f;
#pragma unroll
    for (int j = 0; j < 16; ++j) {
        bm[j] = g_bm[(16 * b + j) * H_ + h];
        m = fmaxf(m, bm[j]);
    }
    float sa[16];
    float gs = 0.f;
#pragma unroll
    for (int j = 0; j < 16; ++j) {
        sa[j] = g_bs[(16 * b + j) * H_ + h] * __expf(bm[j] - m);
        gs += sa[j];
    }
    float4 acc = make_float4(0.f, 0.f, 0.f, 0.f);
#pragma unroll
    for (int j = 0; j < 16; ++j) {
        float r = __expf(bm[j] - m) / fmaxf(gs, sa[j]);
        const float4 v = *(const float4*)(g_o + ((long)((16 * b + j) * H_ + h)) * KV_ + 4 * tid);
        acc.x += r * v.x; acc.y += r * v.y;
        acc.z += r * v.z; acc.w += r * v.w;
    }
    *(float4*)(out + (long)bh * KV_ + 4 * tid) = acc;
}

extern "C" void kernel_launch(void* const* d_in, const int* in_sizes, int n_in,
                              void* d_out, int out_size, void* d_ws, size_t ws_size,
                              hipStream_t stream)
{
    const float* query       = (const float*)d_in[0];
    const float* key_cache   = (const float*)d_in[1];
    // d_in[2] = block_mapping (one-hot of block_groups) — not needed
    const float* block_bias  = (const float*)d_in[3];
    const int*   block_list  = (const int*)d_in[4];
    const int*   block_groups= (const int*)d_in[5];
    float* out = (float*)d_out;

    mla_block_kernel<<<NB_, 256, 0, stream>>>(query, key_cache, block_bias,
                                              block_list, block_groups);
    mla_combine_kernel<<<B_ * H_, 128, 0, stream>>>(out);
}